// Round 19
// baseline (50.220 us; speedup 1.0000x reference)
//
#include <hip/hip_runtime.h>
#include <math.h>

// Problem constants (from reference)
#define M_SLOTS 64
#define E_DIM   64
#define KEY_DIM 64
#define V_DIM   128
#define K_CAT   4
#define S_LEN   200

typedef __attribute__((ext_vector_type(8)))  short short8;
typedef __attribute__((ext_vector_type(16))) float f32x16;

// ---------------- ws layout (float offsets) ----------------
#define OFF_CT     0                          // 4096 ushort = 2048 f  (Ct[m][e] bf16)
#define OFF_BM     2048                       // 64
#define OFF_WBAR   2112                       // 64
#define OFF_BBAR   2176                       // 1
#define OFF_RM0    2240                       // 64
#define OFF_P0     2304                       // 64
#define OFF_WSUM   2368                       // S*M = 12800 (zeroed by k_pre blocks 1..13)
#define OFF_EMSUM  (OFF_WSUM + S_LEN*M_SLOTS) // 200 (contiguous w/ wsum)
#define ZERO_CNT   (S_LEN*M_SLOTS + S_LEN)    // 13000 floats

// pack two f32 -> bf16 pair, round-to-nearest-even (for MFMA inputs)
__device__ __forceinline__ unsigned pk2rne(float lo, float hi) {
    unsigned ul = __float_as_uint(lo); ul += 0x7fffu + ((ul >> 16) & 1u);
    unsigned uh = __float_as_uint(hi); uh += 0x7fffu + ((uh >> 16) & 1u);
    return __builtin_amdgcn_perm(uh, ul, 0x07060302u);
}
__device__ __forceinline__ unsigned short bf16rne(float f) {
    unsigned u = __float_as_uint(f);
    return (unsigned short)((u + 0x7fffu + ((u >> 16) & 1u)) >> 16);
}
__device__ __forceinline__ short8 as_s8(uint4 u) { return __builtin_bit_cast(short8, u); }

__device__ __forceinline__ void gpcm_store(float th, int q,
                                           const float* __restrict__ alpha_mean,
                                           const float* __restrict__ beta_base,
                                           const float* __restrict__ beta_gaps,
                                           float* __restrict__ out, size_t idx) {
    float a  = __expf(alpha_mean[q]);
    float b0 = beta_base[q];
    float2 g = *reinterpret_cast<const float2*>(&beta_gaps[q * (K_CAT - 2)]);
    float g0 = log1pf(__expf(g.x));
    float g1 = log1pf(__expf(g.y));
    float be1 = b0 + g0;
    float be2 = be1 + g1;
    float z0 = a * (th - b0);
    float z1 = a * (th - be1);
    float z2 = a * (th - be2);
    float c1 = z0, c2 = z0 + z1, c3 = z0 + z1 + z2;
    float cm = fmaxf(fmaxf(0.f, c1), fmaxf(c2, c3));
    float e0 = __expf(0.f - cm), e1 = __expf(c1 - cm), e2 = __expf(c2 - cm), e3 = __expf(c3 - cm);
    float si = __fdividef(1.0f, e0 + e1 + e2 + e3);
    float4 o4 = make_float4(e0 * si, e1 * si, e2 * si, e3 * si);
    *reinterpret_cast<float4*>(&out[idx * K_CAT]) = o4;
}

// Gather the lane's q-row slices (issue early to hide latency).
__device__ __forceinline__ void load_qf(const float* __restrict__ qrow, int h, float4 qf[8]) {
    #pragma unroll
    for (int s = 0; s < 4; ++s) {
        const float4* src = (const float4*)(qrow + s * 16 + h * 8);
        qf[2 * s]     = src[0];
        qf[2 * s + 1] = src[1];
    }
}

// Load the lane's 8 Ct A-fragments once (t-invariant).
__device__ __forceinline__ void load_afrags(const unsigned short* __restrict__ ct,
                                            int h, int p, uint4 af[8]) {
    #pragma unroll
    for (int mt = 0; mt < 2; ++mt)
        #pragma unroll
        for (int s = 0; s < 4; ++s)
            af[mt * 4 + s] = *(const uint4*)(ct + (p + 32 * mt) * E_DIM + s * 16 + h * 8);
}

// 32x32x16 MFMA logits from preloaded qf + af: acc[mt][j] = logit for
// m = (j&3) + 8*((j>>2)&3) + 4*h + 32*mt, pair col p.
__device__ __forceinline__ void mfma_logits(
    const float4 qf[8], const uint4 af[8],
    const float* __restrict__ bm, int h, f32x16 acc[2])
{
    #pragma unroll
    for (int mt = 0; mt < 2; ++mt)
        #pragma unroll
        for (int g = 0; g < 4; ++g) {
            float4 v = *(const float4*)(bm + 8 * g + 4 * h + 32 * mt);
            acc[mt][4 * g + 0] = v.x; acc[mt][4 * g + 1] = v.y;
            acc[mt][4 * g + 2] = v.z; acc[mt][4 * g + 3] = v.w;
        }
    #pragma unroll
    for (int s = 0; s < 4; ++s) {
        uint4 bf;
        bf.x = pk2rne(qf[2 * s].x,     qf[2 * s].y);
        bf.y = pk2rne(qf[2 * s].z,     qf[2 * s].w);
        bf.z = pk2rne(qf[2 * s + 1].x, qf[2 * s + 1].y);
        bf.w = pk2rne(qf[2 * s + 1].z, qf[2 * s + 1].w);
        short8 bfr = as_s8(bf);
        acc[0] = __builtin_amdgcn_mfma_f32_32x32x16_bf16(as_s8(af[s]),     bfr, acc[0], 0, 0, 0);
        acc[1] = __builtin_amdgcn_mfma_f32_32x32x16_bf16(as_s8(af[4 + s]), bfr, acc[1], 0, 0, 0);
    }
}

// softmax (64 slots, this lane holds 32) + pair-fold; writes lane's folded
// value (sum over this wave's 32 pairs of attn[m]) into lsFoldRow[m].
__device__ __forceinline__ void softmax_fold(
    const f32x16 acc[2], int lane, int h, float* lsFoldRow)
{
    float av[32];
    float ssum = 0.f;
    #pragma unroll
    for (int j = 0; j < 16; ++j) { av[j]      = __expf(acc[0][j]); ssum += av[j]; }
    #pragma unroll
    for (int j = 0; j < 16; ++j) { av[16 + j] = __expf(acc[1][j]); ssum += av[16 + j]; }
    ssum += __shfl_xor(ssum, 32);
    const float inv = __fdividef(1.0f, ssum);
    #pragma unroll
    for (int j = 0; j < 32; ++j) av[j] *= inv;
    #pragma unroll
    for (int step = 0; step < 5; ++step) {
        const int sh = 1 << step;
        #pragma unroll
        for (int j = 0; j < (32 >> step) / 2; ++j) {
            float p0 = av[2 * j]     + __shfl_xor(av[2 * j], sh);
            float p1 = av[2 * j + 1] + __shfl_xor(av[2 * j + 1], sh);
            av[j] = (lane & sh) ? p1 : p0;
        }
    }
    const int jj = lane & 31;
    const int m = (jj & 3) + 8 * ((jj >> 2) & 3) + 4 * h + 32 * (jj >> 4);
    lsFoldRow[m] = av[0];
}

// logits + theta-dot + GPCM for one t (k_out body).
__device__ __forceinline__ void out_one(
    const float4 qf[8], const uint4 af[8], const float* __restrict__ bm,
    const float* rmP /* slot-permuted rm for this t */, int h, int q,
    const float* __restrict__ alpha_mean, const float* __restrict__ beta_base,
    const float* __restrict__ beta_gaps, float* __restrict__ out, size_t idx)
{
    f32x16 acc[2];
    mfma_logits(qf, af, bm, h, acc);
    const float* rmh = rmP + h * 32;
    float ssum = 0.f, th = 0.f;
    #pragma unroll
    for (int j = 0; j < 16; ++j) {
        float e = __expf(acc[0][j]);
        ssum += e;
        th = fmaf(e, rmh[j], th);
    }
    #pragma unroll
    for (int j = 0; j < 16; ++j) {
        float e = __expf(acc[1][j]);
        ssum += e;
        th = fmaf(e, rmh[16 + j], th);
    }
    ssum += __shfl_xor(ssum, 32);
    th   += __shfl_xor(th, 32);
    th = __fdividef(th, ssum);
    if (!h) gpcm_store(th, q, alpha_mean, beta_base, beta_gaps, out, idx);
}

// k_pre: 14 blocks. Block 0: 4 waves, each one 32x32 Ct tile via MFMA + side
// duties. Blocks 1..13: zero wsum/emsum with float4 stores. (r14-verified)
__global__ __launch_bounds__(256) void k_pre(
    const float* __restrict__ q2k_w, const float* __restrict__ q2k_b,
    const float* __restrict__ mkeys,
    const float* __restrict__ ev_w, const float* __restrict__ ev_b,
    const float* __restrict__ means, const float* __restrict__ logvars,
    float* __restrict__ ws)
{
    const int tid = threadIdx.x;
    if (blockIdx.x != 0) {
        int i = ((int)blockIdx.x - 1) * 1024 + tid * 4;
        if (i + 4 <= ZERO_CNT) {
            *reinterpret_cast<float4*>(ws + OFF_WSUM + i) = make_float4(0.f, 0.f, 0.f, 0.f);
        } else {
            for (int j = i; j < ZERO_CNT; ++j) ws[OFF_WSUM + j] = 0.f;
        }
        return;
    }
    const int wv = tid >> 6, lane = tid & 63;
    const int h = lane >> 5, p = lane & 31;

    {
        const int m0 = (wv & 1) * 32, e0 = (wv >> 1) * 32;
        f32x16 d;
        #pragma unroll
        for (int i = 0; i < 16; ++i) d[i] = 0.f;
        #pragma unroll
        for (int s = 0; s < 4; ++s) {
            const float* ar = mkeys + (m0 + p) * KEY_DIM + s * 16 + h * 8;
            const float* br = q2k_w + (e0 + p) * KEY_DIM + s * 16 + h * 8;
            float4 a0 = *(const float4*)ar, a1 = *(const float4*)(ar + 4);
            float4 b0 = *(const float4*)br, b1 = *(const float4*)(br + 4);
            uint4 au, bu;
            au.x = pk2rne(a0.x, a0.y); au.y = pk2rne(a0.z, a0.w);
            au.z = pk2rne(a1.x, a1.y); au.w = pk2rne(a1.z, a1.w);
            bu.x = pk2rne(b0.x, b0.y); bu.y = pk2rne(b0.z, b0.w);
            bu.z = pk2rne(b1.x, b1.y); bu.w = pk2rne(b1.z, b1.w);
            d = __builtin_amdgcn_mfma_f32_32x32x16_bf16(as_s8(au), as_s8(bu), d, 0, 0, 0);
        }
        unsigned short* ct = (unsigned short*)ws;
        #pragma unroll
        for (int j = 0; j < 16; ++j) {
            int row = (j & 3) + 8 * ((j >> 2) & 3) + 4 * h;
            ct[(m0 + row) * E_DIM + e0 + p] = bf16rne(d[j]);
        }
    }

    if (wv == 0) {          // wbar[e]
        float s = 0.f;
        const float4* er = (const float4*)(ev_w + (size_t)lane * V_DIM);
        #pragma unroll
        for (int i = 0; i < V_DIM / 4; ++i) {
            float4 v = er[i];
            s += (v.x + v.y) + (v.z + v.w);
        }
        ws[OFF_WBAR + lane] = s * (1.0f / V_DIM);
    } else if (wv == 1) {   // bm, bbar
        float s = 0.f;
        const float4* mk = (const float4*)(mkeys + lane * KEY_DIM);
        const float4* qb = (const float4*)q2k_b;
        #pragma unroll
        for (int i = 0; i < KEY_DIM / 4; ++i) {
            float4 a = mk[i], c = qb[i];
            s += a.x * c.x + a.y * c.y + a.z * c.z + a.w * c.w;
        }
        ws[OFF_BM + lane] = s;
        float bbv = ev_b[lane] + ev_b[64 + lane];
        #pragma unroll
        for (int o = 32; o; o >>= 1) bbv += __shfl_xor(bbv, o);
        if (!lane) ws[OFF_BBAR] = bbv * (1.0f / V_DIM);
    } else if (wv == 2) {   // rm0/p0
        float s = 0.f;
        const float4* mr = (const float4*)(means + (size_t)lane * V_DIM);
        #pragma unroll
        for (int i = 0; i < V_DIM / 4; ++i) {
            float4 v = mr[i];
            s += (v.x + v.y) + (v.z + v.w);
        }
        ws[OFF_RM0 + lane] = s * (1.0f / V_DIM);
        ws[OFF_P0 + lane]  = __expf(-logvars[(size_t)lane * V_DIM]);  // row-uniform
    }
}

// Stats: 4 t's per block, grid (S/4, B/128). qs/rs first hop = one int4 line;
// rolling 2-buffer qf prefetch; LDS fold -> 64 atomics per t per block.
__global__ __launch_bounds__(256, 2) void k_attn(
    const float* __restrict__ qtab, const int* __restrict__ qs, const int* __restrict__ rs,
    const float* __restrict__ ws_ro,
    const float* __restrict__ qa_w, const float* __restrict__ qa_b,
    float* __restrict__ wsum, float* __restrict__ emsum,
    int B, float invNQ)
{
    __shared__ float4 lsEv[64];
    __shared__ float lsFold[4][4][M_SLOTS];   // [t][wave][m]
    const int tid = threadIdx.x, wv = tid >> 6, lane = tid & 63;
    const int h = lane >> 5, p = lane & 31;
    const int t0 = blockIdx.x * 4;
    const int b = blockIdx.y * 128 + wv * 32 + p;

    const int4 qv = *reinterpret_cast<const int4*>(&qs[(size_t)b * S_LEN + t0]);
    const int4 rv = *reinterpret_cast<const int4*>(&rs[(size_t)b * S_LEN + t0]);
    float4 qfA[8], qfB[8];
    load_qf(qtab + (size_t)qv.x * E_DIM, h, qfA);
    load_qf(qtab + (size_t)qv.y * E_DIM, h, qfB);

    uint4 af[8];
    load_afrags((const unsigned short*)ws_ro, h, p, af);   // t-invariant

    if (tid < 64) lsEv[tid] = make_float4(qa_w[tid], qa_w[E_DIM + tid], qa_b[tid],
                                          ws_ro[OFF_WBAR + tid]);
    const float bb = ws_ro[OFF_BBAR];
    const float* bm = ws_ro + OFF_BM;

    {   // t0
        f32x16 acc[2];
        mfma_logits(qfA, af, bm, h, acc);
        softmax_fold(acc, lane, h, &lsFold[0][wv][0]);
    }
    load_qf(qtab + (size_t)qv.z * E_DIM, h, qfA);   // prefetch t2
    {   // t1
        f32x16 acc[2];
        mfma_logits(qfB, af, bm, h, acc);
        softmax_fold(acc, lane, h, &lsFold[1][wv][0]);
    }
    load_qf(qtab + (size_t)qv.w * E_DIM, h, qfB);   // prefetch t3
    {   // t2
        f32x16 acc[2];
        mfma_logits(qfA, af, bm, h, acc);
        softmax_fold(acc, lane, h, &lsFold[2][wv][0]);
    }
    {   // t3
        f32x16 acc[2];
        mfma_logits(qfB, af, bm, h, acc);
        softmax_fold(acc, lane, h, &lsFold[3][wv][0]);
    }
    __syncthreads();   // lsEv + lsFold ready

    // wave wv owns t0+wv: one atomic per lane
    {
        float s4 = (lsFold[wv][0][lane] + lsFold[wv][1][lane])
                 + (lsFold[wv][2][lane] + lsFold[wv][3][lane]);
        atomicAdd(&wsum[(t0 + wv) * M_SLOTS + lane], s4);
    }

    // evidence scalars for the 4 t's
    float ev0 = 0.f, ev1 = 0.f, ev2 = 0.f, ev3 = 0.f;
    const float kinv = 1.0f / (K_CAT - 1);
    const float qn0 = (float)qv.x * invNQ, rn0 = (float)rv.x * kinv;
    const float qn1 = (float)qv.y * invNQ, rn1 = (float)rv.y * kinv;
    const float qn2 = (float)qv.z * invNQ, rn2 = (float)rv.z * kinv;
    const float qn3 = (float)qv.w * invNQ, rn3 = (float)rv.w * kinv;
    #pragma unroll 8
    for (int e = 0; e < 32; ++e) {
        float4 pv = lsEv[h * 32 + e];
        float qa0 = fmaf(qn0, pv.x, fmaf(rn0, pv.y, pv.z));
        float qa1 = fmaf(qn1, pv.x, fmaf(rn1, pv.y, pv.z));
        float qa2 = fmaf(qn2, pv.x, fmaf(rn2, pv.y, pv.z));
        float qa3 = fmaf(qn3, pv.x, fmaf(rn3, pv.y, pv.z));
        float ez0 = __expf(2.0f * qa0), ez1 = __expf(2.0f * qa1);
        float ez2 = __expf(2.0f * qa2), ez3 = __expf(2.0f * qa3);
        ev0 = fmaf(__fdividef(ez0 - 1.0f, ez0 + 1.0f), pv.w, ev0);
        ev1 = fmaf(__fdividef(ez1 - 1.0f, ez1 + 1.0f), pv.w, ev1);
        ev2 = fmaf(__fdividef(ez2 - 1.0f, ez2 + 1.0f), pv.w, ev2);
        ev3 = fmaf(__fdividef(ez3 - 1.0f, ez3 + 1.0f), pv.w, ev3);
    }
    ev0 += __shfl_xor(ev0, 32); ev0 += bb;
    ev1 += __shfl_xor(ev1, 32); ev1 += bb;
    ev2 += __shfl_xor(ev2, 32); ev2 += bb;
    ev3 += __shfl_xor(ev3, 32); ev3 += bb;
    #pragma unroll
    for (int o = 16; o; o >>= 1) {
        ev0 += __shfl_xor(ev0, o); ev1 += __shfl_xor(ev1, o);
        ev2 += __shfl_xor(ev2, o); ev3 += __shfl_xor(ev3, o);
    }
    if (!lane) {
        atomicAdd(&emsum[t0 + 0], ev0);
        atomicAdd(&emsum[t0 + 1], ev1);
        atomicAdd(&emsum[t0 + 2], ev2);
        atomicAdd(&emsum[t0 + 3], ev3);
    }
}

// Output: 4 t's per block. Prefix once for t0 (4-way unrolled, 4-wave split);
// t1..t3 incremental. Rolling qf prefetch; A-frags hoisted.
__global__ __launch_bounds__(256, 2) void k_out(
    const float* __restrict__ qtab, const int* __restrict__ qs,
    const float* __restrict__ ws_ro,
    const float* __restrict__ alpha_mean, const float* __restrict__ beta_base,
    const float* __restrict__ beta_gaps, float* __restrict__ out, int B, float invB)
{
    __shared__ float lsW[4][M_SLOTS], lsN[4][M_SLOTS];
    __shared__ float lsRmP[4][M_SLOTS];
    const int tid = threadIdx.x, wv = tid >> 6, lane = tid & 63;
    const int h = lane >> 5, p = lane & 31;
    const int t0 = blockIdx.x * 4;
    const int b = blockIdx.y * 128 + wv * 32 + p;

    const int4 qv = *reinterpret_cast<const int4*>(&qs[(size_t)b * S_LEN + t0]);
    float4 qfA[8], qfB[8];
    load_qf(qtab + (size_t)qv.x * E_DIM, h, qfA);   // issue gathers BEFORE prefix
    load_qf(qtab + (size_t)qv.y * E_DIM, h, qfB);

    uint4 af[8];
    load_afrags((const unsigned short*)ws_ro, h, p, af);   // t-invariant

    // prefix partials over [0, t0): wave wv sums its segment, 4-way unrolled
    {
        const float* wsum  = ws_ro + OFF_WSUM;
        const float* emsum = ws_ro + OFF_EMSUM;
        const int seg = (t0 + 3) >> 2;
        const int s0 = wv * seg, s1 = min(s0 + seg, t0);
        float pw0 = 0.f, pn0 = 0.f, pw1 = 0.f, pn1 = 0.f;
        float pw2 = 0.f, pn2 = 0.f, pw3 = 0.f, pn3 = 0.f;
        int s = s0;
        for (; s + 4 <= s1; s += 4) {
            float w0 = wsum[(s + 0) * M_SLOTS + lane];
            float w1 = wsum[(s + 1) * M_SLOTS + lane];
            float w2 = wsum[(s + 2) * M_SLOTS + lane];
            float w3 = wsum[(s + 3) * M_SLOTS + lane];
            float e0 = emsum[s + 0], e1 = emsum[s + 1];
            float e2 = emsum[s + 2], e3 = emsum[s + 3];
            pw0 += w0; pn0 = fmaf(e0, w0, pn0);
            pw1 += w1; pn1 = fmaf(e1, w1, pn1);
            pw2 += w2; pn2 = fmaf(e2, w2, pn2);
            pw3 += w3; pn3 = fmaf(e3, w3, pn3);
        }
        for (; s < s1; ++s) {
            float w = wsum[s * M_SLOTS + lane];
            pw0 += w; pn0 = fmaf(emsum[s], w, pn0);
        }
        lsW[wv][lane] = (pw0 + pw1) + (pw2 + pw3);
        lsN[wv][lane] = (pn0 + pn1) + (pn2 + pn3);
    }
    __syncthreads();
    if (tid < 64) {
        const int m = tid;
        float sw = lsW[0][m] + lsW[1][m] + lsW[2][m] + lsW[3][m];
        float sn = lsN[0][m] + lsN[1][m] + lsN[2][m] + lsN[3][m];
        const float p0v = ws_ro[OFF_P0 + m];
        const float i2 = invB * invB;
        float den = p0v + sw * invB;
        float num = fmaf(p0v, ws_ro[OFF_RM0 + m], sn * i2);
        // MFMA slot-permuted index: idx = h(m)*32 + mt(m)*16 + j(m)
        const int idx = ((m >> 2) & 1) * 32 + ((m >> 5) & 1) * 16 + (m & 3) + 4 * ((m >> 3) & 3);
        lsRmP[0][idx] = num / den;
        #pragma unroll
        for (int k = 0; k < 3; ++k) {     // incremental steps t0+k -> rm for t0+k+1
            float wstep = ws_ro[OFF_WSUM + (t0 + k) * M_SLOTS + m];
            float estep = ws_ro[OFF_EMSUM + t0 + k];
            den += wstep * invB;
            num = fmaf(estep * wstep, i2, num);
            lsRmP[k + 1][idx] = num / den;
        }
    }
    __syncthreads();

    const float* bm = ws_ro + OFF_BM;
    const size_t obase = (size_t)b * S_LEN;
    out_one(qfA, af, bm, lsRmP[0], h, qv.x, alpha_mean, beta_base, beta_gaps, out, obase + t0);
    load_qf(qtab + (size_t)qv.z * E_DIM, h, qfA);   // prefetch t2
    out_one(qfB, af, bm, lsRmP[1], h, qv.y, alpha_mean, beta_base, beta_gaps, out, obase + t0 + 1);
    load_qf(qtab + (size_t)qv.w * E_DIM, h, qfB);   // prefetch t3
    out_one(qfA, af, bm, lsRmP[2], h, qv.z, alpha_mean, beta_base, beta_gaps, out, obase + t0 + 2);
    out_one(qfB, af, bm, lsRmP[3], h, qv.w, alpha_mean, beta_base, beta_gaps, out, obase + t0 + 3);
}

extern "C" void kernel_launch(void* const* d_in, const int* in_sizes, int n_in,
                              void* d_out, int out_size, void* d_ws, size_t ws_size,
                              hipStream_t stream) {
    const float* qtab       = (const float*)d_in[0];
    const float* alpha_mean = (const float*)d_in[1];
    const float* beta_base  = (const float*)d_in[2];
    const float* beta_gaps  = (const float*)d_in[3];
    const float* ab_means   = (const float*)d_in[4];
    const float* ab_logvars = (const float*)d_in[5];
    const float* mkeys      = (const float*)d_in[6];
    const float* q2k_w      = (const float*)d_in[7];
    const float* q2k_b      = (const float*)d_in[8];
    const float* qa_w       = (const float*)d_in[9];
    const float* qa_b       = (const float*)d_in[10];
    const float* ev_w       = (const float*)d_in[11];
    const float* ev_b       = (const float*)d_in[12];
    const int*   qs         = (const int*)d_in[13];
    const int*   rs         = (const int*)d_in[14];
    float* out = (float*)d_out;
    float* ws  = (float*)d_ws;

    const int NQ = in_sizes[1];
    const int S  = S_LEN;
    const int B  = in_sizes[13] / S;   // 512

    float* wsum  = ws + OFF_WSUM;
    float* emsum = ws + OFF_EMSUM;

    k_pre<<<14, 256, 0, stream>>>(q2k_w, q2k_b, mkeys, ev_w, ev_b,
                                  ab_means, ab_logvars, ws);

    dim3 g(S / 4, B / 128);
    k_attn<<<g, 256, 0, stream>>>(qtab, qs, rs, ws, qa_w, qa_b,
                                  wsum, emsum, B, 1.0f / (float)NQ);

    k_out<<<g, 256, 0, stream>>>(qtab, qs, ws, alpha_mean, beta_base,
                                 beta_gaps, out, B, 1.0f / (float)B);
}

// Round 20
// 45.539 us; speedup vs baseline: 1.1028x; 1.1028x over previous
//
#include <hip/hip_runtime.h>
#include <math.h>

// Problem constants (from reference)
#define M_SLOTS 64
#define E_DIM   64
#define KEY_DIM 64
#define V_DIM   128
#define K_CAT   4
#define S_LEN   200

typedef __attribute__((ext_vector_type(8)))  short short8;
typedef __attribute__((ext_vector_type(16))) float f32x16;

// ---------------- ws layout (float offsets) ----------------
#define OFF_CT     0                          // 4096 ushort = 2048 f  (Ct[m][e] bf16)
#define OFF_BM     2048                       // 64
#define OFF_WBAR   2112                       // 64
#define OFF_BBAR   2176                       // 1
#define OFF_RM0    2240                       // 64
#define OFF_P0     2304                       // 64
#define OFF_WSUM   2368                       // S*M = 12800 (zeroed by k_pre blocks 1..13)
#define OFF_EMSUM  (OFF_WSUM + S_LEN*M_SLOTS) // 200 (contiguous w/ wsum)
#define ZERO_CNT   (S_LEN*M_SLOTS + S_LEN)    // 13000 floats

// pack two f32 -> bf16 pair, round-to-nearest-even (for MFMA inputs)
__device__ __forceinline__ unsigned pk2rne(float lo, float hi) {
    unsigned ul = __float_as_uint(lo); ul += 0x7fffu + ((ul >> 16) & 1u);
    unsigned uh = __float_as_uint(hi); uh += 0x7fffu + ((uh >> 16) & 1u);
    return __builtin_amdgcn_perm(uh, ul, 0x07060302u);
}
__device__ __forceinline__ unsigned short bf16rne(float f) {
    unsigned u = __float_as_uint(f);
    return (unsigned short)((u + 0x7fffu + ((u >> 16) & 1u)) >> 16);
}
__device__ __forceinline__ short8 as_s8(uint4 u) { return __builtin_bit_cast(short8, u); }

// XCD-aware bijective remap for grid (100,4): 400 blocks = 8 XCDs x 50.
// Gives each XCD a contiguous tx-slice so shared qs/rs lines + the wsum
// prefix working set stay XCD-local in L2.
__device__ __forceinline__ void xcd_remap(int bx, int by, int& tx, int& yb) {
    int flat = bx + 100 * by;          // HW linear id (x fastest)
    int nf = (flat & 7) * 50 + (flat >> 3);
    tx = nf % 100;
    yb = nf / 100;
}

__device__ __forceinline__ void gpcm_store(float th, int q,
                                           const float* __restrict__ alpha_mean,
                                           const float* __restrict__ beta_base,
                                           const float* __restrict__ beta_gaps,
                                           float* __restrict__ out, size_t idx) {
    float a  = __expf(alpha_mean[q]);
    float b0 = beta_base[q];
    float2 g = *reinterpret_cast<const float2*>(&beta_gaps[q * (K_CAT - 2)]);
    float g0 = log1pf(__expf(g.x));
    float g1 = log1pf(__expf(g.y));
    float be1 = b0 + g0;
    float be2 = be1 + g1;
    float z0 = a * (th - b0);
    float z1 = a * (th - be1);
    float z2 = a * (th - be2);
    float c1 = z0, c2 = z0 + z1, c3 = z0 + z1 + z2;
    float cm = fmaxf(fmaxf(0.f, c1), fmaxf(c2, c3));
    float e0 = __expf(0.f - cm), e1 = __expf(c1 - cm), e2 = __expf(c2 - cm), e3 = __expf(c3 - cm);
    float si = __fdividef(1.0f, e0 + e1 + e2 + e3);
    float4 o4 = make_float4(e0 * si, e1 * si, e2 * si, e3 * si);
    *reinterpret_cast<float4*>(&out[idx * K_CAT]) = o4;
}

// Gather the lane's q-row slices (issue early to hide latency).
__device__ __forceinline__ void load_qf(const float* __restrict__ qrow, int h, float4 qf[8]) {
    #pragma unroll
    for (int s = 0; s < 4; ++s) {
        const float4* src = (const float4*)(qrow + s * 16 + h * 8);
        qf[2 * s]     = src[0];
        qf[2 * s + 1] = src[1];
    }
}

// Load the lane's 8 Ct A-fragments once (t-invariant).
__device__ __forceinline__ void load_afrags(const unsigned short* __restrict__ ct,
                                            int h, int p, uint4 af[8]) {
    #pragma unroll
    for (int mt = 0; mt < 2; ++mt)
        #pragma unroll
        for (int s = 0; s < 4; ++s)
            af[mt * 4 + s] = *(const uint4*)(ct + (p + 32 * mt) * E_DIM + s * 16 + h * 8);
}

// 32x32x16 MFMA logits from preloaded qf + af: acc[mt][j] = logit for
// m = (j&3) + 8*((j>>2)&3) + 4*h + 32*mt, pair col p.
__device__ __forceinline__ void mfma_logits(
    const float4 qf[8], const uint4 af[8],
    const float* __restrict__ bm, int h, f32x16 acc[2])
{
    #pragma unroll
    for (int mt = 0; mt < 2; ++mt)
        #pragma unroll
        for (int g = 0; g < 4; ++g) {
            float4 v = *(const float4*)(bm + 8 * g + 4 * h + 32 * mt);
            acc[mt][4 * g + 0] = v.x; acc[mt][4 * g + 1] = v.y;
            acc[mt][4 * g + 2] = v.z; acc[mt][4 * g + 3] = v.w;
        }
    #pragma unroll
    for (int s = 0; s < 4; ++s) {
        uint4 bf;
        bf.x = pk2rne(qf[2 * s].x,     qf[2 * s].y);
        bf.y = pk2rne(qf[2 * s].z,     qf[2 * s].w);
        bf.z = pk2rne(qf[2 * s + 1].x, qf[2 * s + 1].y);
        bf.w = pk2rne(qf[2 * s + 1].z, qf[2 * s + 1].w);
        short8 bfr = as_s8(bf);
        acc[0] = __builtin_amdgcn_mfma_f32_32x32x16_bf16(as_s8(af[s]),     bfr, acc[0], 0, 0, 0);
        acc[1] = __builtin_amdgcn_mfma_f32_32x32x16_bf16(as_s8(af[4 + s]), bfr, acc[1], 0, 0, 0);
    }
}

// softmax (64 slots, this lane holds 32) + pair-fold; writes lane's folded
// value (sum over this wave's 32 pairs of attn[m]) into lsFoldRow[m].
__device__ __forceinline__ void softmax_fold(
    const f32x16 acc[2], int lane, int h, float* lsFoldRow)
{
    float av[32];
    float ssum = 0.f;
    #pragma unroll
    for (int j = 0; j < 16; ++j) { av[j]      = __expf(acc[0][j]); ssum += av[j]; }
    #pragma unroll
    for (int j = 0; j < 16; ++j) { av[16 + j] = __expf(acc[1][j]); ssum += av[16 + j]; }
    ssum += __shfl_xor(ssum, 32);
    const float inv = __fdividef(1.0f, ssum);
    #pragma unroll
    for (int j = 0; j < 32; ++j) av[j] *= inv;
    #pragma unroll
    for (int step = 0; step < 5; ++step) {
        const int sh = 1 << step;
        #pragma unroll
        for (int j = 0; j < (32 >> step) / 2; ++j) {
            float p0 = av[2 * j]     + __shfl_xor(av[2 * j], sh);
            float p1 = av[2 * j + 1] + __shfl_xor(av[2 * j + 1], sh);
            av[j] = (lane & sh) ? p1 : p0;
        }
    }
    const int jj = lane & 31;
    const int m = (jj & 3) + 8 * ((jj >> 2) & 3) + 4 * h + 32 * (jj >> 4);
    lsFoldRow[m] = av[0];
}

// k_pre: 14 blocks. Block 0: 4 waves, each one 32x32 Ct tile via MFMA + side
// duties. Blocks 1..13: zero wsum/emsum with float4 stores. (r14-verified)
__global__ __launch_bounds__(256) void k_pre(
    const float* __restrict__ q2k_w, const float* __restrict__ q2k_b,
    const float* __restrict__ mkeys,
    const float* __restrict__ ev_w, const float* __restrict__ ev_b,
    const float* __restrict__ means, const float* __restrict__ logvars,
    float* __restrict__ ws)
{
    const int tid = threadIdx.x;
    if (blockIdx.x != 0) {
        int i = ((int)blockIdx.x - 1) * 1024 + tid * 4;
        if (i + 4 <= ZERO_CNT) {
            *reinterpret_cast<float4*>(ws + OFF_WSUM + i) = make_float4(0.f, 0.f, 0.f, 0.f);
        } else {
            for (int j = i; j < ZERO_CNT; ++j) ws[OFF_WSUM + j] = 0.f;
        }
        return;
    }
    const int wv = tid >> 6, lane = tid & 63;
    const int h = lane >> 5, p = lane & 31;

    {
        const int m0 = (wv & 1) * 32, e0 = (wv >> 1) * 32;
        f32x16 d;
        #pragma unroll
        for (int i = 0; i < 16; ++i) d[i] = 0.f;
        #pragma unroll
        for (int s = 0; s < 4; ++s) {
            const float* ar = mkeys + (m0 + p) * KEY_DIM + s * 16 + h * 8;
            const float* br = q2k_w + (e0 + p) * KEY_DIM + s * 16 + h * 8;
            float4 a0 = *(const float4*)ar, a1 = *(const float4*)(ar + 4);
            float4 b0 = *(const float4*)br, b1 = *(const float4*)(br + 4);
            uint4 au, bu;
            au.x = pk2rne(a0.x, a0.y); au.y = pk2rne(a0.z, a0.w);
            au.z = pk2rne(a1.x, a1.y); au.w = pk2rne(a1.z, a1.w);
            bu.x = pk2rne(b0.x, b0.y); bu.y = pk2rne(b0.z, b0.w);
            bu.z = pk2rne(b1.x, b1.y); bu.w = pk2rne(b1.z, b1.w);
            d = __builtin_amdgcn_mfma_f32_32x32x16_bf16(as_s8(au), as_s8(bu), d, 0, 0, 0);
        }
        unsigned short* ct = (unsigned short*)ws;
        #pragma unroll
        for (int j = 0; j < 16; ++j) {
            int row = (j & 3) + 8 * ((j >> 2) & 3) + 4 * h;
            ct[(m0 + row) * E_DIM + e0 + p] = bf16rne(d[j]);
        }
    }

    if (wv == 0) {          // wbar[e]
        float s = 0.f;
        const float4* er = (const float4*)(ev_w + (size_t)lane * V_DIM);
        #pragma unroll
        for (int i = 0; i < V_DIM / 4; ++i) {
            float4 v = er[i];
            s += (v.x + v.y) + (v.z + v.w);
        }
        ws[OFF_WBAR + lane] = s * (1.0f / V_DIM);
    } else if (wv == 1) {   // bm, bbar
        float s = 0.f;
        const float4* mk = (const float4*)(mkeys + lane * KEY_DIM);
        const float4* qb = (const float4*)q2k_b;
        #pragma unroll
        for (int i = 0; i < KEY_DIM / 4; ++i) {
            float4 a = mk[i], c = qb[i];
            s += a.x * c.x + a.y * c.y + a.z * c.z + a.w * c.w;
        }
        ws[OFF_BM + lane] = s;
        float bbv = ev_b[lane] + ev_b[64 + lane];
        #pragma unroll
        for (int o = 32; o; o >>= 1) bbv += __shfl_xor(bbv, o);
        if (!lane) ws[OFF_BBAR] = bbv * (1.0f / V_DIM);
    } else if (wv == 2) {   // rm0/p0
        float s = 0.f;
        const float4* mr = (const float4*)(means + (size_t)lane * V_DIM);
        #pragma unroll
        for (int i = 0; i < V_DIM / 4; ++i) {
            float4 v = mr[i];
            s += (v.x + v.y) + (v.z + v.w);
        }
        ws[OFF_RM0 + lane] = s * (1.0f / V_DIM);
        ws[OFF_P0 + lane]  = __expf(-logvars[(size_t)lane * V_DIM]);  // row-uniform
    }
}

// Stats: 2 t's per block. A-frags hoisted; 4-wave LDS fold -> 128 atomics/block.
__global__ __launch_bounds__(256, 3) void k_attn(
    const float* __restrict__ qtab, const int* __restrict__ qs, const int* __restrict__ rs,
    const float* __restrict__ ws_ro,
    const float* __restrict__ qa_w, const float* __restrict__ qa_b,
    float* __restrict__ wsum, float* __restrict__ emsum,
    int B, float invNQ)
{
    __shared__ float4 lsEv[64];
    __shared__ float lsFold[2][4][M_SLOTS];
    const int tid = threadIdx.x, wv = tid >> 6, lane = tid & 63;
    const int h = lane >> 5, p = lane & 31;
    int tx, yb;
    xcd_remap(blockIdx.x, blockIdx.y, tx, yb);
    const int t0 = tx * 2, t1 = t0 + 1;
    const int b = yb * 128 + wv * 32 + p;

    const int q0 = qs[(size_t)b * S_LEN + t0];
    const int r0 = rs[(size_t)b * S_LEN + t0];
    const int q1 = qs[(size_t)b * S_LEN + t1];   // same line as t0
    const int r1 = rs[(size_t)b * S_LEN + t1];
    float4 qf0[8], qf1[8];
    load_qf(qtab + (size_t)q0 * E_DIM, h, qf0);  // both gathers in flight
    load_qf(qtab + (size_t)q1 * E_DIM, h, qf1);

    uint4 af[8];
    load_afrags((const unsigned short*)ws_ro, h, p, af);   // t-invariant

    if (tid < 64) lsEv[tid] = make_float4(qa_w[tid], qa_w[E_DIM + tid], qa_b[tid],
                                          ws_ro[OFF_WBAR + tid]);
    const float bb = ws_ro[OFF_BBAR];

    {
        f32x16 acc[2];
        mfma_logits(qf0, af, ws_ro + OFF_BM, h, acc);
        softmax_fold(acc, lane, h, &lsFold[0][wv][0]);
    }
    {
        f32x16 acc[2];
        mfma_logits(qf1, af, ws_ro + OFF_BM, h, acc);
        softmax_fold(acc, lane, h, &lsFold[1][wv][0]);
    }

    __syncthreads();   // lsEv + lsFold ready

    if (wv < 2) {      // wave 0 -> t0, wave 1 -> t1: one atomic per lane
        float s4 = (lsFold[wv][0][lane] + lsFold[wv][1][lane])
                 + (lsFold[wv][2][lane] + lsFold[wv][3][lane]);
        atomicAdd(&wsum[(wv ? t1 : t0) * M_SLOTS + lane], s4);
    }

    // evidence scalars for both t's
    float ev0 = 0.f, ev1 = 0.f;
    const float qn0 = (float)q0 * invNQ, rn0 = (float)r0 * (1.0f / (K_CAT - 1));
    const float qn1 = (float)q1 * invNQ, rn1 = (float)r1 * (1.0f / (K_CAT - 1));
    #pragma unroll 8
    for (int e = 0; e < 32; ++e) {
        float4 pv = lsEv[h * 32 + e];
        float qa0 = fmaf(qn0, pv.x, fmaf(rn0, pv.y, pv.z));
        float qa1 = fmaf(qn1, pv.x, fmaf(rn1, pv.y, pv.z));
        float ez0 = __expf(2.0f * qa0);
        float ez1 = __expf(2.0f * qa1);
        ev0 = fmaf(__fdividef(ez0 - 1.0f, ez0 + 1.0f), pv.w, ev0);
        ev1 = fmaf(__fdividef(ez1 - 1.0f, ez1 + 1.0f), pv.w, ev1);
    }
    ev0 += __shfl_xor(ev0, 32); ev0 += bb;
    ev1 += __shfl_xor(ev1, 32); ev1 += bb;
    #pragma unroll
    for (int o = 16; o; o >>= 1) { ev0 += __shfl_xor(ev0, o); ev1 += __shfl_xor(ev1, o); }
    if (!lane) {
        atomicAdd(&emsum[t0], ev0);
        atomicAdd(&emsum[t1], ev1);
    }
}

// Output: 2 t's per block. Prefix 4-way unrolled (4 independent accumulator
// pairs); t1's rm = t0's + one step. A-frags hoisted.
__global__ __launch_bounds__(256, 3) void k_out(
    const float* __restrict__ qtab, const int* __restrict__ qs,
    const float* __restrict__ ws_ro,
    const float* __restrict__ alpha_mean, const float* __restrict__ beta_base,
    const float* __restrict__ beta_gaps, float* __restrict__ out, int B, float invB)
{
    __shared__ float lsW[4][M_SLOTS], lsN[4][M_SLOTS];
    __shared__ float lsRmP0[M_SLOTS], lsRmP1[M_SLOTS];
    const int tid = threadIdx.x, wv = tid >> 6, lane = tid & 63;
    const int h = lane >> 5, p = lane & 31;
    int tx, yb;
    xcd_remap(blockIdx.x, blockIdx.y, tx, yb);
    const int t0 = tx * 2, t1 = t0 + 1;
    const int b = yb * 128 + wv * 32 + p;

    const int q0 = qs[(size_t)b * S_LEN + t0];
    const int q1 = qs[(size_t)b * S_LEN + t1];
    float4 qf0[8], qf1[8];
    load_qf(qtab + (size_t)q0 * E_DIM, h, qf0);  // issue gathers BEFORE prefix
    load_qf(qtab + (size_t)q1 * E_DIM, h, qf1);

    uint4 af[8];
    load_afrags((const unsigned short*)ws_ro, h, p, af);   // t-invariant

    // prefix partials over [0, t0): wave wv sums its segment, 4-way unrolled
    {
        const float* wsum  = ws_ro + OFF_WSUM;
        const float* emsum = ws_ro + OFF_EMSUM;
        const int seg = (t0 + 3) >> 2;
        const int s0 = wv * seg, s1 = min(s0 + seg, t0);
        float pw0 = 0.f, pn0 = 0.f, pw1 = 0.f, pn1 = 0.f;
        float pw2 = 0.f, pn2 = 0.f, pw3 = 0.f, pn3 = 0.f;
        int s = s0;
        for (; s + 4 <= s1; s += 4) {
            float w0 = wsum[(s + 0) * M_SLOTS + lane];
            float w1 = wsum[(s + 1) * M_SLOTS + lane];
            float w2 = wsum[(s + 2) * M_SLOTS + lane];
            float w3 = wsum[(s + 3) * M_SLOTS + lane];
            float e0 = emsum[s + 0], e1 = emsum[s + 1];
            float e2 = emsum[s + 2], e3 = emsum[s + 3];
            pw0 += w0; pn0 = fmaf(e0, w0, pn0);
            pw1 += w1; pn1 = fmaf(e1, w1, pn1);
            pw2 += w2; pn2 = fmaf(e2, w2, pn2);
            pw3 += w3; pn3 = fmaf(e3, w3, pn3);
        }
        for (; s < s1; ++s) {
            float w = wsum[s * M_SLOTS + lane];
            pw0 += w; pn0 = fmaf(emsum[s], w, pn0);
        }
        lsW[wv][lane] = (pw0 + pw1) + (pw2 + pw3);
        lsN[wv][lane] = (pn0 + pn1) + (pn2 + pn3);
    }
    __syncthreads();
    if (tid < 64) {
        const int m = tid;
        float sw = lsW[0][m] + lsW[1][m] + lsW[2][m] + lsW[3][m];
        float sn = lsN[0][m] + lsN[1][m] + lsN[2][m] + lsN[3][m];
        const float p0v = ws_ro[OFF_P0 + m];
        float den0 = p0v + sw * invB;
        float num0 = fmaf(p0v, ws_ro[OFF_RM0 + m], sn * (invB * invB));
        // one more step for t1: include stats of step t0
        float wstep = ws_ro[OFF_WSUM + t0 * M_SLOTS + m];
        float estep = ws_ro[OFF_EMSUM + t0];
        float den1 = den0 + wstep * invB;
        float num1 = fmaf(estep * wstep, invB * invB, num0);
        // MFMA slot-permuted index: idx = h(m)*32 + mt(m)*16 + j(m)
        const int idx = ((m >> 2) & 1) * 32 + ((m >> 5) & 1) * 16 + (m & 3) + 4 * ((m >> 3) & 3);
        lsRmP0[idx] = num0 / den0;
        lsRmP1[idx] = num1 / den1;
    }
    __syncthreads();

    #pragma unroll
    for (int it = 0; it < 2; ++it) {
        f32x16 acc[2];
        mfma_logits(it ? qf1 : qf0, af, ws_ro + OFF_BM, h, acc);
        const float* rmh = (it ? lsRmP1 : lsRmP0) + h * 32;
        float ssum = 0.f, th = 0.f;
        #pragma unroll
        for (int j = 0; j < 16; ++j) {
            float e = __expf(acc[0][j]);
            ssum += e;
            th = fmaf(e, rmh[j], th);
        }
        #pragma unroll
        for (int j = 0; j < 16; ++j) {
            float e = __expf(acc[1][j]);
            ssum += e;
            th = fmaf(e, rmh[16 + j], th);
        }
        ssum += __shfl_xor(ssum, 32);
        th   += __shfl_xor(th, 32);
        th = __fdividef(th, ssum);
        if (!h) {
            const int t = it ? t1 : t0;
            const int q = it ? q1 : q0;
            gpcm_store(th, q, alpha_mean, beta_base, beta_gaps, out, (size_t)b * S_LEN + t);
        }
    }
}

extern "C" void kernel_launch(void* const* d_in, const int* in_sizes, int n_in,
                              void* d_out, int out_size, void* d_ws, size_t ws_size,
                              hipStream_t stream) {
    const float* qtab       = (const float*)d_in[0];
    const float* alpha_mean = (const float*)d_in[1];
    const float* beta_base  = (const float*)d_in[2];
    const float* beta_gaps  = (const float*)d_in[3];
    const float* ab_means   = (const float*)d_in[4];
    const float* ab_logvars = (const float*)d_in[5];
    const float* mkeys      = (const float*)d_in[6];
    const float* q2k_w      = (const float*)d_in[7];
    const float* q2k_b      = (const float*)d_in[8];
    const float* qa_w       = (const float*)d_in[9];
    const float* qa_b       = (const float*)d_in[10];
    const float* ev_w       = (const float*)d_in[11];
    const float* ev_b       = (const float*)d_in[12];
    const int*   qs         = (const int*)d_in[13];
    const int*   rs         = (const int*)d_in[14];
    float* out = (float*)d_out;
    float* ws  = (float*)d_ws;

    const int NQ = in_sizes[1];
    const int S  = S_LEN;
    const int B  = in_sizes[13] / S;   // 512

    float* wsum  = ws + OFF_WSUM;
    float* emsum = ws + OFF_EMSUM;

    k_pre<<<14, 256, 0, stream>>>(q2k_w, q2k_b, mkeys, ev_w, ev_b,
                                  ab_means, ab_logvars, ws);

    dim3 g(S / 2, B / 128);
    k_attn<<<g, 256, 0, stream>>>(qtab, qs, rs, ws, qa_w, qa_b,
                                  wsum, emsum, B, 1.0f / (float)NQ);

    k_out<<<g, 256, 0, stream>>>(qtab, qs, ws, alpha_mean, beta_base,
                                 beta_gaps, out, B, 1.0f / (float)B);
}

// Round 21
// 44.545 us; speedup vs baseline: 1.1274x; 1.0223x over previous
//
#include <hip/hip_runtime.h>
#include <math.h>

// Problem constants (from reference)
#define M_SLOTS 64
#define E_DIM   64
#define KEY_DIM 64
#define V_DIM   128
#define K_CAT   4
#define S_LEN   200

typedef __attribute__((ext_vector_type(8)))  short short8;
typedef __attribute__((ext_vector_type(16))) float f32x16;

// ---------------- ws layout (float offsets) ----------------
#define OFF_CT     0                          // 4096 ushort = 2048 f  (Ct[m][e] bf16)
#define OFF_BM     2048                       // 64
#define OFF_WBAR   2112                       // 64
#define OFF_BBAR   2176                       // 1
#define OFF_RM0    2240                       // 64
#define OFF_P0     2304                       // 64
#define OFF_WSUM   2368                       // S*M = 12800 (zeroed by k_pre blocks 1..13)
#define OFF_EMSUM  (OFF_WSUM + S_LEN*M_SLOTS) // 200 (contiguous w/ wsum)
#define ZERO_CNT   (S_LEN*M_SLOTS + S_LEN)    // 13000 floats

// pack two f32 -> bf16 pair, round-to-nearest-even (for MFMA inputs)
__device__ __forceinline__ unsigned pk2rne(float lo, float hi) {
    unsigned ul = __float_as_uint(lo); ul += 0x7fffu + ((ul >> 16) & 1u);
    unsigned uh = __float_as_uint(hi); uh += 0x7fffu + ((uh >> 16) & 1u);
    return __builtin_amdgcn_perm(uh, ul, 0x07060302u);
}
__device__ __forceinline__ unsigned short bf16rne(float f) {
    unsigned u = __float_as_uint(f);
    return (unsigned short)((u + 0x7fffu + ((u >> 16) & 1u)) >> 16);
}
__device__ __forceinline__ short8 as_s8(uint4 u) { return __builtin_bit_cast(short8, u); }

__device__ __forceinline__ void gpcm_store(float th, int q,
                                           const float* __restrict__ alpha_mean,
                                           const float* __restrict__ beta_base,
                                           const float* __restrict__ beta_gaps,
                                           float* __restrict__ out, size_t idx) {
    float a  = __expf(alpha_mean[q]);
    float b0 = beta_base[q];
    float2 g = *reinterpret_cast<const float2*>(&beta_gaps[q * (K_CAT - 2)]);
    float g0 = log1pf(__expf(g.x));
    float g1 = log1pf(__expf(g.y));
    float be1 = b0 + g0;
    float be2 = be1 + g1;
    float z0 = a * (th - b0);
    float z1 = a * (th - be1);
    float z2 = a * (th - be2);
    float c1 = z0, c2 = z0 + z1, c3 = z0 + z1 + z2;
    float cm = fmaxf(fmaxf(0.f, c1), fmaxf(c2, c3));
    float e0 = __expf(0.f - cm), e1 = __expf(c1 - cm), e2 = __expf(c2 - cm), e3 = __expf(c3 - cm);
    float si = __fdividef(1.0f, e0 + e1 + e2 + e3);
    float4 o4 = make_float4(e0 * si, e1 * si, e2 * si, e3 * si);
    *reinterpret_cast<float4*>(&out[idx * K_CAT]) = o4;
}

// Gather the lane's q-row slices (issue early to hide latency).
__device__ __forceinline__ void load_qf(const float* __restrict__ qrow, int h, float4 qf[8]) {
    #pragma unroll
    for (int s = 0; s < 4; ++s) {
        const float4* src = (const float4*)(qrow + s * 16 + h * 8);
        qf[2 * s]     = src[0];
        qf[2 * s + 1] = src[1];
    }
}

// Load the lane's 8 Ct A-fragments once (t-invariant).
__device__ __forceinline__ void load_afrags(const unsigned short* __restrict__ ct,
                                            int h, int p, uint4 af[8]) {
    #pragma unroll
    for (int mt = 0; mt < 2; ++mt)
        #pragma unroll
        for (int s = 0; s < 4; ++s)
            af[mt * 4 + s] = *(const uint4*)(ct + (p + 32 * mt) * E_DIM + s * 16 + h * 8);
}

// 32x32x16 MFMA logits from preloaded qf + af: acc[mt][j] = logit for
// m = (j&3) + 8*((j>>2)&3) + 4*h + 32*mt, pair col p.
__device__ __forceinline__ void mfma_logits(
    const float4 qf[8], const uint4 af[8],
    const float* __restrict__ bm, int h, f32x16 acc[2])
{
    #pragma unroll
    for (int mt = 0; mt < 2; ++mt)
        #pragma unroll
        for (int g = 0; g < 4; ++g) {
            float4 v = *(const float4*)(bm + 8 * g + 4 * h + 32 * mt);
            acc[mt][4 * g + 0] = v.x; acc[mt][4 * g + 1] = v.y;
            acc[mt][4 * g + 2] = v.z; acc[mt][4 * g + 3] = v.w;
        }
    #pragma unroll
    for (int s = 0; s < 4; ++s) {
        uint4 bf;
        bf.x = pk2rne(qf[2 * s].x,     qf[2 * s].y);
        bf.y = pk2rne(qf[2 * s].z,     qf[2 * s].w);
        bf.z = pk2rne(qf[2 * s + 1].x, qf[2 * s + 1].y);
        bf.w = pk2rne(qf[2 * s + 1].z, qf[2 * s + 1].w);
        short8 bfr = as_s8(bf);
        acc[0] = __builtin_amdgcn_mfma_f32_32x32x16_bf16(as_s8(af[s]),     bfr, acc[0], 0, 0, 0);
        acc[1] = __builtin_amdgcn_mfma_f32_32x32x16_bf16(as_s8(af[4 + s]), bfr, acc[1], 0, 0, 0);
    }
}

// softmax (64 slots, this lane holds 32) + pair-fold; writes lane's folded
// value (sum over this wave's 32 pairs of attn[m]) into lsFoldRow[m].
__device__ __forceinline__ void softmax_fold(
    const f32x16 acc[2], int lane, int h, float* lsFoldRow)
{
    float av[32];
    float ssum = 0.f;
    #pragma unroll
    for (int j = 0; j < 16; ++j) { av[j]      = __expf(acc[0][j]); ssum += av[j]; }
    #pragma unroll
    for (int j = 0; j < 16; ++j) { av[16 + j] = __expf(acc[1][j]); ssum += av[16 + j]; }
    ssum += __shfl_xor(ssum, 32);
    const float inv = __fdividef(1.0f, ssum);
    #pragma unroll
    for (int j = 0; j < 32; ++j) av[j] *= inv;
    #pragma unroll
    for (int step = 0; step < 5; ++step) {
        const int sh = 1 << step;
        #pragma unroll
        for (int j = 0; j < (32 >> step) / 2; ++j) {
            float p0 = av[2 * j]     + __shfl_xor(av[2 * j], sh);
            float p1 = av[2 * j + 1] + __shfl_xor(av[2 * j + 1], sh);
            av[j] = (lane & sh) ? p1 : p0;
        }
    }
    const int jj = lane & 31;
    const int m = (jj & 3) + 8 * ((jj >> 2) & 3) + 4 * h + 32 * (jj >> 4);
    lsFoldRow[m] = av[0];
}

// k_pre: 14 blocks. Block 0: 4 waves, each one 32x32 Ct tile via MFMA + side
// duties. Blocks 1..13: zero wsum/emsum with float4 stores. (r14-verified)
__global__ __launch_bounds__(256) void k_pre(
    const float* __restrict__ q2k_w, const float* __restrict__ q2k_b,
    const float* __restrict__ mkeys,
    const float* __restrict__ ev_w, const float* __restrict__ ev_b,
    const float* __restrict__ means, const float* __restrict__ logvars,
    float* __restrict__ ws)
{
    const int tid = threadIdx.x;
    if (blockIdx.x != 0) {
        int i = ((int)blockIdx.x - 1) * 1024 + tid * 4;
        if (i + 4 <= ZERO_CNT) {
            *reinterpret_cast<float4*>(ws + OFF_WSUM + i) = make_float4(0.f, 0.f, 0.f, 0.f);
        } else {
            for (int j = i; j < ZERO_CNT; ++j) ws[OFF_WSUM + j] = 0.f;
        }
        return;
    }
    const int wv = tid >> 6, lane = tid & 63;
    const int h = lane >> 5, p = lane & 31;

    {
        const int m0 = (wv & 1) * 32, e0 = (wv >> 1) * 32;
        f32x16 d;
        #pragma unroll
        for (int i = 0; i < 16; ++i) d[i] = 0.f;
        #pragma unroll
        for (int s = 0; s < 4; ++s) {
            const float* ar = mkeys + (m0 + p) * KEY_DIM + s * 16 + h * 8;
            const float* br = q2k_w + (e0 + p) * KEY_DIM + s * 16 + h * 8;
            float4 a0 = *(const float4*)ar, a1 = *(const float4*)(ar + 4);
            float4 b0 = *(const float4*)br, b1 = *(const float4*)(br + 4);
            uint4 au, bu;
            au.x = pk2rne(a0.x, a0.y); au.y = pk2rne(a0.z, a0.w);
            au.z = pk2rne(a1.x, a1.y); au.w = pk2rne(a1.z, a1.w);
            bu.x = pk2rne(b0.x, b0.y); bu.y = pk2rne(b0.z, b0.w);
            bu.z = pk2rne(b1.x, b1.y); bu.w = pk2rne(b1.z, b1.w);
            d = __builtin_amdgcn_mfma_f32_32x32x16_bf16(as_s8(au), as_s8(bu), d, 0, 0, 0);
        }
        unsigned short* ct = (unsigned short*)ws;
        #pragma unroll
        for (int j = 0; j < 16; ++j) {
            int row = (j & 3) + 8 * ((j >> 2) & 3) + 4 * h;
            ct[(m0 + row) * E_DIM + e0 + p] = bf16rne(d[j]);
        }
    }

    if (wv == 0) {          // wbar[e]
        float s = 0.f;
        const float4* er = (const float4*)(ev_w + (size_t)lane * V_DIM);
        #pragma unroll
        for (int i = 0; i < V_DIM / 4; ++i) {
            float4 v = er[i];
            s += (v.x + v.y) + (v.z + v.w);
        }
        ws[OFF_WBAR + lane] = s * (1.0f / V_DIM);
    } else if (wv == 1) {   // bm, bbar
        float s = 0.f;
        const float4* mk = (const float4*)(mkeys + lane * KEY_DIM);
        const float4* qb = (const float4*)q2k_b;
        #pragma unroll
        for (int i = 0; i < KEY_DIM / 4; ++i) {
            float4 a = mk[i], c = qb[i];
            s += a.x * c.x + a.y * c.y + a.z * c.z + a.w * c.w;
        }
        ws[OFF_BM + lane] = s;
        float bbv = ev_b[lane] + ev_b[64 + lane];
        #pragma unroll
        for (int o = 32; o; o >>= 1) bbv += __shfl_xor(bbv, o);
        if (!lane) ws[OFF_BBAR] = bbv * (1.0f / V_DIM);
    } else if (wv == 2) {   // rm0/p0
        float s = 0.f;
        const float4* mr = (const float4*)(means + (size_t)lane * V_DIM);
        #pragma unroll
        for (int i = 0; i < V_DIM / 4; ++i) {
            float4 v = mr[i];
            s += (v.x + v.y) + (v.z + v.w);
        }
        ws[OFF_RM0 + lane] = s * (1.0f / V_DIM);
        ws[OFF_P0 + lane]  = __expf(-logvars[(size_t)lane * V_DIM]);  // row-uniform
    }
}

// Stats: 2 t's per block. A-frags hoisted; 4-wave LDS fold -> 128 atomics/block.
__global__ __launch_bounds__(256, 3) void k_attn(
    const float* __restrict__ qtab, const int* __restrict__ qs, const int* __restrict__ rs,
    const float* __restrict__ ws_ro,
    const float* __restrict__ qa_w, const float* __restrict__ qa_b,
    float* __restrict__ wsum, float* __restrict__ emsum,
    int B, float invNQ)
{
    __shared__ float4 lsEv[64];
    __shared__ float lsFold[2][4][M_SLOTS];
    const int tid = threadIdx.x, wv = tid >> 6, lane = tid & 63;
    const int h = lane >> 5, p = lane & 31;
    const int t0 = blockIdx.x * 2, t1 = t0 + 1;
    const int b = blockIdx.y * 128 + wv * 32 + p;

    const int q0 = qs[(size_t)b * S_LEN + t0];
    const int r0 = rs[(size_t)b * S_LEN + t0];
    const int q1 = qs[(size_t)b * S_LEN + t1];   // same line as t0
    const int r1 = rs[(size_t)b * S_LEN + t1];
    float4 qf0[8], qf1[8];
    load_qf(qtab + (size_t)q0 * E_DIM, h, qf0);  // both gathers in flight
    load_qf(qtab + (size_t)q1 * E_DIM, h, qf1);

    uint4 af[8];
    load_afrags((const unsigned short*)ws_ro, h, p, af);   // t-invariant

    if (tid < 64) lsEv[tid] = make_float4(qa_w[tid], qa_w[E_DIM + tid], qa_b[tid],
                                          ws_ro[OFF_WBAR + tid]);
    const float bb = ws_ro[OFF_BBAR];

    {
        f32x16 acc[2];
        mfma_logits(qf0, af, ws_ro + OFF_BM, h, acc);
        softmax_fold(acc, lane, h, &lsFold[0][wv][0]);
    }
    {
        f32x16 acc[2];
        mfma_logits(qf1, af, ws_ro + OFF_BM, h, acc);
        softmax_fold(acc, lane, h, &lsFold[1][wv][0]);
    }

    __syncthreads();   // lsEv + lsFold ready

    if (wv < 2) {      // wave 0 -> t0, wave 1 -> t1: one atomic per lane
        float s4 = (lsFold[wv][0][lane] + lsFold[wv][1][lane])
                 + (lsFold[wv][2][lane] + lsFold[wv][3][lane]);
        atomicAdd(&wsum[(wv ? t1 : t0) * M_SLOTS + lane], s4);
    }

    // evidence scalars for both t's
    float ev0 = 0.f, ev1 = 0.f;
    const float qn0 = (float)q0 * invNQ, rn0 = (float)r0 * (1.0f / (K_CAT - 1));
    const float qn1 = (float)q1 * invNQ, rn1 = (float)r1 * (1.0f / (K_CAT - 1));
    #pragma unroll 8
    for (int e = 0; e < 32; ++e) {
        float4 pv = lsEv[h * 32 + e];
        float qa0 = fmaf(qn0, pv.x, fmaf(rn0, pv.y, pv.z));
        float qa1 = fmaf(qn1, pv.x, fmaf(rn1, pv.y, pv.z));
        float ez0 = __expf(2.0f * qa0);
        float ez1 = __expf(2.0f * qa1);
        ev0 = fmaf(__fdividef(ez0 - 1.0f, ez0 + 1.0f), pv.w, ev0);
        ev1 = fmaf(__fdividef(ez1 - 1.0f, ez1 + 1.0f), pv.w, ev1);
    }
    ev0 += __shfl_xor(ev0, 32); ev0 += bb;
    ev1 += __shfl_xor(ev1, 32); ev1 += bb;
    #pragma unroll
    for (int o = 16; o; o >>= 1) { ev0 += __shfl_xor(ev0, o); ev1 += __shfl_xor(ev1, o); }
    if (!lane) {
        atomicAdd(&emsum[t0], ev0);
        atomicAdd(&emsum[t1], ev1);
    }
}

// Output: 2 t's per block. Prefix 4-way unrolled (4 independent accumulator
// pairs -> exposed L3 latency /4); t1's rm = t0's + one step. A-frags hoisted.
__global__ __launch_bounds__(256, 3) void k_out(
    const float* __restrict__ qtab, const int* __restrict__ qs,
    const float* __restrict__ ws_ro,
    const float* __restrict__ alpha_mean, const float* __restrict__ beta_base,
    const float* __restrict__ beta_gaps, float* __restrict__ out, int B, float invB)
{
    __shared__ float lsW[4][M_SLOTS], lsN[4][M_SLOTS];
    __shared__ float lsRmP0[M_SLOTS], lsRmP1[M_SLOTS];
    const int tid = threadIdx.x, wv = tid >> 6, lane = tid & 63;
    const int h = lane >> 5, p = lane & 31;
    const int t0 = blockIdx.x * 2, t1 = t0 + 1;
    const int b = blockIdx.y * 128 + wv * 32 + p;

    const int q0 = qs[(size_t)b * S_LEN + t0];
    const int q1 = qs[(size_t)b * S_LEN + t1];
    float4 qf0[8], qf1[8];
    load_qf(qtab + (size_t)q0 * E_DIM, h, qf0);  // issue gathers BEFORE prefix
    load_qf(qtab + (size_t)q1 * E_DIM, h, qf1);

    uint4 af[8];
    load_afrags((const unsigned short*)ws_ro, h, p, af);   // t-invariant

    // prefix partials over [0, t0): wave wv sums its segment, 4-way unrolled
    {
        const float* wsum  = ws_ro + OFF_WSUM;
        const float* emsum = ws_ro + OFF_EMSUM;
        const int seg = (t0 + 3) >> 2;
        const int s0 = wv * seg, s1 = min(s0 + seg, t0);
        float pw0 = 0.f, pn0 = 0.f, pw1 = 0.f, pn1 = 0.f;
        float pw2 = 0.f, pn2 = 0.f, pw3 = 0.f, pn3 = 0.f;
        int s = s0;
        for (; s + 4 <= s1; s += 4) {
            float w0 = wsum[(s + 0) * M_SLOTS + lane];
            float w1 = wsum[(s + 1) * M_SLOTS + lane];
            float w2 = wsum[(s + 2) * M_SLOTS + lane];
            float w3 = wsum[(s + 3) * M_SLOTS + lane];
            float e0 = emsum[s + 0], e1 = emsum[s + 1];
            float e2 = emsum[s + 2], e3 = emsum[s + 3];
            pw0 += w0; pn0 = fmaf(e0, w0, pn0);
            pw1 += w1; pn1 = fmaf(e1, w1, pn1);
            pw2 += w2; pn2 = fmaf(e2, w2, pn2);
            pw3 += w3; pn3 = fmaf(e3, w3, pn3);
        }
        for (; s < s1; ++s) {
            float w = wsum[s * M_SLOTS + lane];
            pw0 += w; pn0 = fmaf(emsum[s], w, pn0);
        }
        lsW[wv][lane] = (pw0 + pw1) + (pw2 + pw3);
        lsN[wv][lane] = (pn0 + pn1) + (pn2 + pn3);
    }
    __syncthreads();
    if (tid < 64) {
        const int m = tid;
        float sw = lsW[0][m] + lsW[1][m] + lsW[2][m] + lsW[3][m];
        float sn = lsN[0][m] + lsN[1][m] + lsN[2][m] + lsN[3][m];
        const float p0v = ws_ro[OFF_P0 + m];
        float den0 = p0v + sw * invB;
        float num0 = fmaf(p0v, ws_ro[OFF_RM0 + m], sn * (invB * invB));
        // one more step for t1: include stats of step t0
        float wstep = ws_ro[OFF_WSUM + t0 * M_SLOTS + m];
        float estep = ws_ro[OFF_EMSUM + t0];
        float den1 = den0 + wstep * invB;
        float num1 = fmaf(estep * wstep, invB * invB, num0);
        // MFMA slot-permuted index: idx = h(m)*32 + mt(m)*16 + j(m)
        const int idx = ((m >> 2) & 1) * 32 + ((m >> 5) & 1) * 16 + (m & 3) + 4 * ((m >> 3) & 3);
        lsRmP0[idx] = num0 / den0;
        lsRmP1[idx] = num1 / den1;
    }
    __syncthreads();

    #pragma unroll
    for (int it = 0; it < 2; ++it) {
        f32x16 acc[2];
        mfma_logits(it ? qf1 : qf0, af, ws_ro + OFF_BM, h, acc);
        const float* rmh = (it ? lsRmP1 : lsRmP0) + h * 32;
        float ssum = 0.f, th = 0.f;
        #pragma unroll
        for (int j = 0; j < 16; ++j) {
            float e = __expf(acc[0][j]);
            ssum += e;
            th = fmaf(e, rmh[j], th);
        }
        #pragma unroll
        for (int j = 0; j < 16; ++j) {
            float e = __expf(acc[1][j]);
            ssum += e;
            th = fmaf(e, rmh[16 + j], th);
        }
        ssum += __shfl_xor(ssum, 32);
        th   += __shfl_xor(th, 32);
        th = __fdividef(th, ssum);
        if (!h) {
            const int t = it ? t1 : t0;
            const int q = it ? q1 : q0;
            gpcm_store(th, q, alpha_mean, beta_base, beta_gaps, out, (size_t)b * S_LEN + t);
        }
    }
}

extern "C" void kernel_launch(void* const* d_in, const int* in_sizes, int n_in,
                              void* d_out, int out_size, void* d_ws, size_t ws_size,
                              hipStream_t stream) {
    const float* qtab       = (const float*)d_in[0];
    const float* alpha_mean = (const float*)d_in[1];
    const float* beta_base  = (const float*)d_in[2];
    const float* beta_gaps  = (const float*)d_in[3];
    const float* ab_means   = (const float*)d_in[4];
    const float* ab_logvars = (const float*)d_in[5];
    const float* mkeys      = (const float*)d_in[6];
    const float* q2k_w      = (const float*)d_in[7];
    const float* q2k_b      = (const float*)d_in[8];
    const float* qa_w       = (const float*)d_in[9];
    const float* qa_b       = (const float*)d_in[10];
    const float* ev_w       = (const float*)d_in[11];
    const float* ev_b       = (const float*)d_in[12];
    const int*   qs         = (const int*)d_in[13];
    const int*   rs         = (const int*)d_in[14];
    float* out = (float*)d_out;
    float* ws  = (float*)d_ws;

    const int NQ = in_sizes[1];
    const int S  = S_LEN;
    const int B  = in_sizes[13] / S;   // 512

    float* wsum  = ws + OFF_WSUM;
    float* emsum = ws + OFF_EMSUM;

    k_pre<<<14, 256, 0, stream>>>(q2k_w, q2k_b, mkeys, ev_w, ev_b,
                                  ab_means, ab_logvars, ws);

    dim3 g(S / 2, B / 128);
    k_attn<<<g, 256, 0, stream>>>(qtab, qs, rs, ws, qa_w, qa_b,
                                  wsum, emsum, B, 1.0f / (float)NQ);

    k_out<<<g, 256, 0, stream>>>(qtab, qs, ws, alpha_mean, beta_base,
                                 beta_gaps, out, B, 1.0f / (float)B);
}